// Round 6
// baseline (9126.340 us; speedup 1.0000x reference)
//
#include <hip/hip_runtime.h>
#include <math.h>

// Problem dims
#define BSZ   128
#define TLEN  256
#define NCLS  128
#define WDIM  512
#define XDIM  640       // NC + WD
#define G4    2048      // 4*UNITS

// Geometry: 8 batch-groups (XCD-local) x 32 j-tiles = 256 blocks, 512 threads
#define BT    16        // batch rows per group
#define JTS   16        // h columns per block
#define NBLK  256
#define NTHR  512
#define KCH   8         // chunk length (steps of x-projection kept in regs)

// ws layout (float offsets) — total ~4.7 MB (IC-resident)
// R10: logits atomicAdd (32-way contended IC RMW, ~65k ops/group/step — the
// ~16-20us/step floor) replaced by per-block PRIVATE partial slots + read-
// reduce at argmax. No zeroing needed; double- (not triple-) buffered.
#define H_OFF     0                   // 2 * 128 * 512 h double buffer
#define LPART_OFF 131072              // 2 buf * 256 blk * 16 * 128 partials
#define W0_OFF    1179648             // 2048: bias + 1e-5*colsum(W[640:768])
#define FLAG_OFF  1181696             // 256 flags, stride 16 u32 (64B lines)

typedef unsigned long long ull;

__device__ __forceinline__ float sigmoidf_(float x) {
  return 1.0f / (1.0f + expf(-x));
}

// relaxed device-scope 16B load as 2x b64 atomics (IC-coherent, NO buffer_inv)
__device__ __forceinline__ float4 ld_dev16(const float* p) {
  const ull* q = (const ull*)p;
  ull a = __hip_atomic_load(q,     __ATOMIC_RELAXED, __HIP_MEMORY_SCOPE_AGENT);
  ull b = __hip_atomic_load(q + 1, __ATOMIC_RELAXED, __HIP_MEMORY_SCOPE_AGENT);
  float4 r;
  ((ull*)&r)[0] = a;
  ((ull*)&r)[1] = b;
  return r;
}

// relaxed device-scope 16B store as 2x b64 atomics (lands at IC, no RMW)
__device__ __forceinline__ void st_dev16(float* p, float4 v) {
  ull* q = (ull*)p;
  __hip_atomic_store(q,     ((ull*)&v)[0], __ATOMIC_RELAXED, __HIP_MEMORY_SCOPE_AGENT);
  __hip_atomic_store(q + 1, ((ull*)&v)[1], __ATOMIC_RELAXED, __HIP_MEMORY_SCOPE_AGENT);
}

__global__ void setup_kernel(const float* __restrict__ W,
                             const float* __restrict__ bias,
                             float* __restrict__ ws) {
  int tid = blockIdx.x * blockDim.x + threadIdx.x;   // 64*256 = 16384 threads
  if (tid < 4096)
    ((unsigned int*)(ws + FLAG_OFF))[tid] = 0u;
  if (tid < G4) {
    float s = 0.0f;
    #pragma unroll 4
    for (int r = 0; r < NCLS; ++r)
      s += W[(size_t)(XDIM + r) * G4 + tid];
    ws[W0_OFF + tid] = bias[tid] + 1e-5f * s;
  }
}

__global__ void __launch_bounds__(NTHR, 1)
lstm_main(const float* __restrict__ xc, const float* __restrict__ xw,
          const float* __restrict__ W,  const float* __restrict__ U,
          const float* __restrict__ bias, const float* __restrict__ Wsm,
          const float* __restrict__ bsv, int* __restrict__ out,
          float* __restrict__ ws)
{
  __shared__ float U_lds[512 * 64];      // 128 KB resident U tile [k][cc]
  __shared__ float ins_lds[2][2176];     // staging/zred; chunk GEMM W-tile alias
  __shared__ float wsm_lds[16 * 128];    // resident Wsm tile [j][m]
  __shared__ float hl_lds[16 * 17];      // h_new tile [b][16], padded
  __shared__ int   idx_lds[BT];

  float* zred  = &ins_lds[0][0];         // z exchange [32][68] (2176 floats)
  float* Wt    = &ins_lds[0][0];         // chunk GEMM W-tile [64][64] (4096 fl)
  float* red_v = zred;                   // argmax scratch [16][33]
  int*   red_i = (int*)(zred + 528);     // [16][33]

  const int tid = threadIdx.x;
  const int blk = blockIdx.x;
  // XCD-local groups: round-robin dispatch -> blk&7 selects XCD (perf heuristic
  // only; correctness relies solely on memory-side relaxed atomics)
  const int grp = blk & 7;               // batch group
  const int jt  = blk >> 3;              // 0..31 j-tile
  const int b0  = grp * BT;
  const int j0  = jt * JTS;

  // GEMM mapping: thread = (batch row gb, gate gg, 4-col group j4, K-half kh)
  const int gb  = tid & 15;
  const int gg  = (tid >> 4) & 3;
  const int j4  = (tid >> 6) & 3;
  const int kh  = tid >> 8;                 // 0..1
  const int c0  = gg * 512 + j0 + j4 * 4;   // global column in [0,2048)
  const int cc0 = gg * 16 + j4 * 4;         // LDS column in [0,64)

  // staging mapping: thread = (row srow, 4-float seg sseg)
  const int srow = tid >> 5;                // 0..15
  const int sseg = tid & 31;                // 0..31

  // logits/argmax mapping: thread = (row ub, class-quad um)
  const int ub = tid >> 5;
  const int um = tid & 31;

  // update mapping (tid < 256): thread = (row vb, h-col vj)
  const int vb = (tid >> 4) & 15;
  const int vj = tid & 15;

  float* hbuf   = ws + H_OFF;
  float* lpart  = ws + LPART_OFF;
  unsigned int* flags = (unsigned int*)(ws + FLAG_OFF);
  unsigned int* myflag   = flags + (grp * 32 + jt) * 16;
  unsigned int* pollflag = flags + (grp * 32 + (tid & 31)) * 16;

  // Load resident U tile: U_lds[k*64 + cc] = U[k][col(cc)]
  {
    int cc  = tid & 63;
    int col = (cc >> 4) * 512 + j0 + (cc & 15);
    int k0  = tid >> 6;  // 0..7
    for (int kk = 0; kk < 64; ++kk) {
      int k = kk * 8 + k0;
      U_lds[k * 64 + cc] = U[(size_t)k * G4 + col];
    }
  }
  // Load resident Wsm tile: wsm_lds[j][m]
  {
    int row = tid >> 5, col4 = tid & 31;
    *(float4*)(&wsm_lds[row * 128 + col4 * 4]) =
        *(const float4*)(Wsm + (size_t)(j0 + row) * NCLS + col4 * 4);
  }

  // ---- chunk GEMM (R9 SB=4 s-blocked, proven clean + equal-perf):
  // per k-quad, 4 NAMED float4 W values read once from LDS, reused across
  // 4 steps -> 640 ds_read_b128/thread/chunk. SCRATCH DISCIPLINE (ledger):
  // compile-time local-array indices only; hot set ~80 VGPR; sched_barrier
  // caps load clustering. FMA order = R0's -> bitwise-identical.
  float4 xq[KCH];
  auto chunk_gemm = [&](int tt0) {
    #pragma unroll
    for (int s = 0; s < KCH; ++s) xq[s] = make_float4(0.f, 0.f, 0.f, 0.f);
    #pragma unroll 1
    for (int kt = 0; kt < 10; ++kt) {          // ten 64-deep k-tiles
      // stage W-tile [64 k][64 cols] -> Wt (2 float4 per thread)
      int id0 = tid,       k0t = id0 >> 4, cg0 = id0 & 15;
      int id1 = tid + 512, k1t = id1 >> 4, cg1 = id1 & 15;
      int col0 = (cg0 >> 2) * 512 + j0 + (cg0 & 3) * 4;
      int col1 = (cg1 >> 2) * 512 + j0 + (cg1 & 3) * 4;
      float4 wv0 = *(const float4*)(W + (size_t)(kt * 64 + k0t) * G4 + col0);
      float4 wv1 = *(const float4*)(W + (size_t)(kt * 64 + k1t) * G4 + col1);
      __syncthreads();                         // prior Wt readers done
      *(float4*)(Wt + k0t * 64 + cg0 * 4) = wv0;
      *(float4*)(Wt + k1t * 64 + cg1 * 4) = wv1;
      __syncthreads();                         // tile visible
      const float* wp = Wt + (kh * 32) * 64 + cc0;
      const float* xb0 = (kt < 2)
        ? xc + ((size_t)(b0 + gb) * TLEN + tt0) * NCLS + kt * 64 + kh * 32
        : xw + ((size_t)(b0 + gb) * TLEN + tt0) * WDIM + (kt * 64 - 128) + kh * 32;
      const size_t xstr = (kt < 2) ? (size_t)NCLS : (size_t)WDIM;
      #pragma unroll
      for (int sb = 0; sb < 2; ++sb) {         // two s-blocks of 4 steps
        #pragma unroll 1
        for (int q = 0; q < 8; ++q) {          // 8 k-quads of this K-half
          const float* wq = wp + q * 4 * 64;
          float4 w0 = *(const float4*)(wq);
          float4 w1 = *(const float4*)(wq + 64);
          float4 w2 = *(const float4*)(wq + 128);
          float4 w3 = *(const float4*)(wq + 192);
          const float* xquad = xb0 + (size_t)(sb * 4) * xstr + q * 4;
          #pragma unroll
          for (int u = 0; u < 4; ++u) {
            const int s = sb * 4 + u;          // compile-time index
            float4 xa = *(const float4*)(xquad + (size_t)u * xstr);
            xq[s].x = fmaf(xa.x, w0.x, xq[s].x);
            xq[s].y = fmaf(xa.x, w0.y, xq[s].y);
            xq[s].z = fmaf(xa.x, w0.z, xq[s].z);
            xq[s].w = fmaf(xa.x, w0.w, xq[s].w);
            xq[s].x = fmaf(xa.y, w1.x, xq[s].x);
            xq[s].y = fmaf(xa.y, w1.y, xq[s].y);
            xq[s].z = fmaf(xa.y, w1.z, xq[s].z);
            xq[s].w = fmaf(xa.y, w1.w, xq[s].w);
            xq[s].x = fmaf(xa.z, w2.x, xq[s].x);
            xq[s].y = fmaf(xa.z, w2.y, xq[s].y);
            xq[s].z = fmaf(xa.z, w2.z, xq[s].z);
            xq[s].w = fmaf(xa.z, w2.w, xq[s].w);
            xq[s].x = fmaf(xa.w, w3.x, xq[s].x);
            xq[s].y = fmaf(xa.w, w3.y, xq[s].y);
            xq[s].z = fmaf(xa.w, w3.z, xq[s].z);
            xq[s].w = fmaf(xa.w, w3.w, xq[s].w);
          }
          __builtin_amdgcn_sched_barrier(0);   // cap load clustering here
        }
      }
    }
  };

  float creg = 0.0f;      // cell state: thread(<256) owns (b0+vb, j0+vj)

  __syncthreads();        // U_lds / wsm_lds ready
  chunk_gemm(0);          // steps 0..7
  __syncthreads();        // Wt readers done before zred reuse

  for (int t = 0; t < TLEN; ++t) {
    float4 acc = xq[0];
    #pragma unroll
    for (int s = 0; s < KCH - 1; ++s) xq[s] = xq[s + 1];   // shift register

    if (t == 0) {
      if (kh == 0) {
        const float4 w0 = *(const float4*)(ws + W0_OFF + c0);
        acc.x += w0.x; acc.y += w0.y; acc.z += w0.z; acc.w += w0.w;
      }
    } else {
      // ---- argmax of step t-1: read the group's 32 PRIVATE partial slots
      // from IC and sum (no atomics, no zeroing). 4 independent float4
      // accumulators; unroll 1 -> <=8 loads in flight (scratch-safe).
      {
        const float* pb = lpart
            + (((size_t)((t - 1) & 1) * NBLK) + grp * 32) * (BT * NCLS)
            + (size_t)ub * NCLS + um * 4;
        float4 s0 = make_float4(0.f, 0.f, 0.f, 0.f);
        float4 s1 = s0, s2 = s0, s3 = s0;
        #pragma unroll 1
        for (int j2 = 0; j2 < 32; j2 += 4) {
          float4 a = ld_dev16(pb + (size_t)(j2 + 0) * (BT * NCLS));
          float4 b = ld_dev16(pb + (size_t)(j2 + 1) * (BT * NCLS));
          float4 c = ld_dev16(pb + (size_t)(j2 + 2) * (BT * NCLS));
          float4 d = ld_dev16(pb + (size_t)(j2 + 3) * (BT * NCLS));
          s0.x += a.x; s0.y += a.y; s0.z += a.z; s0.w += a.w;
          s1.x += b.x; s1.y += b.y; s1.z += b.z; s1.w += b.w;
          s2.x += c.x; s2.y += c.y; s2.z += c.z; s2.w += c.w;
          s3.x += d.x; s3.y += d.y; s3.z += d.z; s3.w += d.w;
        }
        float4 lv;
        lv.x = (s0.x + s1.x) + (s2.x + s3.x);
        lv.y = (s0.y + s1.y) + (s2.y + s3.y);
        lv.z = (s0.z + s1.z) + (s2.z + s3.z);
        lv.w = (s0.w + s1.w) + (s2.w + s3.w);
        const float4 bb = *(const float4*)(bsv + um * 4);
        float bv = lv.x + bb.x; int bi = um * 4;
        if (lv.y + bb.y > bv) { bv = lv.y + bb.y; bi = um * 4 + 1; }
        if (lv.z + bb.z > bv) { bv = lv.z + bb.z; bi = um * 4 + 2; }
        if (lv.w + bb.w > bv) { bv = lv.w + bb.w; bi = um * 4 + 3; }
        red_v[ub * 33 + um] = bv; red_i[ub * 33 + um] = bi;
        __syncthreads();
        if (um == 0) {
          float v = red_v[ub * 33]; int vi = red_i[ub * 33];
          #pragma unroll
          for (int s = 1; s < 32; ++s) {     // first-max tie-break via idx order
            float v2 = red_v[ub * 33 + s];
            int   i2 = red_i[ub * 33 + s];
            if (v2 > v || (v2 == v && i2 < vi)) { v = v2; vi = i2; }
          }
          idx_lds[ub] = vi;
          if (jt == 0) out[(b0 + ub) * TLEN + (t - 1)] = vi;
        }
        __syncthreads();
      }
      // ---- bias + one-hot word row of W (K-half 0 only)
      if (kh == 0) {
        int wr = XDIM + idx_lds[gb];
        const float4 b4 = *(const float4*)(bias + c0);
        const float4 w4 = *(const float4*)(W + (size_t)wr * G4 + c0);
        acc.x += b4.x + w4.x;  acc.y += b4.y + w4.y;
        acc.z += b4.z + w4.z;  acc.w += b4.w + w4.w;
      }
      // ---- h @ U from LDS-resident tile (double-buffered h staging;
      //      h loads are relaxed device-scope atomics -> IC-fresh, no inv)
      //      R0-VERBATIM. The explicit-float4 rewrite (R7) exposed 5
      //      clustered b128 loads x 16 unrolled iters -> xq spilled to
      //      scratch (~70GB traffic). Do not "vectorize" this loop.
      {
        const float* hprev = hbuf + ((t + 1) & 1) * (BSZ * 512);
        {
          float4 r = ld_dev16(hprev + (size_t)(b0 + srow) * 512 + sseg * 4);
          *(float4*)(&ins_lds[0][srow * 132 + sseg * 4]) = r;
          __syncthreads();
        }
        #pragma unroll 1
        for (int ch = 0; ch < 4; ++ch) {
          float4 nxt;
          if (ch + 1 < 4) {
            nxt = ld_dev16(hprev + (size_t)(b0 + srow) * 512
                           + (ch + 1) * 128 + sseg * 4);
          }
          const float* up = U_lds + (ch * 128 + kh * 64) * 64 + cc0;
          const float* ip = &ins_lds[ch & 1][gb * 132 + kh * 64];
          #pragma unroll 8
          for (int kk = 0; kk < 64; ++kk) {
            float a = ip[kk];
            float4 u4 = *(const float4*)(up + kk * 64);
            acc.x = fmaf(a, u4.x, acc.x);
            acc.y = fmaf(a, u4.y, acc.y);
            acc.z = fmaf(a, u4.z, acc.z);
            acc.w = fmaf(a, u4.w, acc.w);
          }
          if (ch + 1 < 4) {
            *(float4*)(&ins_lds[(ch + 1) & 1][srow * 132 + sseg * 4]) = nxt;
            __syncthreads();
          }
        }
      }
    }

    // ---- z exchange into zred (= ins_lds[0]; its last readers synced at ch2)
    *(float4*)(zred + (gb * 2 + kh) * 68 + cc0) = acc;
    __syncthreads();

    // ---- gate nonlinearities + cell/hidden update (first 256 threads)
    if (tid < 256) {
      float zi = zred[(vb * 2) * 68 +  0 + vj] + zred[(vb * 2 + 1) * 68 +  0 + vj];
      float zf = zred[(vb * 2) * 68 + 16 + vj] + zred[(vb * 2 + 1) * 68 + 16 + vj];
      float zg = zred[(vb * 2) * 68 + 32 + vj] + zred[(vb * 2 + 1) * 68 + 32 + vj];
      float zo = zred[(vb * 2) * 68 + 48 + vj] + zred[(vb * 2 + 1) * 68 + 48 + vj];
      float iv = sigmoidf_(zi);
      float fv = sigmoidf_(zf);
      float gv = tanhf(zg);
      float ov = sigmoidf_(zo);
      creg = fv * creg + iv * gv;
      float hn = ov * tanhf(creg);
      // relaxed device-scope store -> lands at IC, visible after vmcnt drain
      __hip_atomic_store(hbuf + (t & 1) * (BSZ * 512)
                         + (size_t)(b0 + vb) * 512 + j0 + vj, hn,
                         __ATOMIC_RELAXED, __HIP_MEMORY_SCOPE_AGENT);
      hl_lds[vb * 17 + vj] = hn;
    }
    __syncthreads();

    // ---- logits partial over this block's 16 j -> PRIVATE slot store
    // (plain relaxed device-scope stores; replaces 2048 contended atomicAdds
    //  per block per step — the 32-way IC RMW serialization that was the
    //  ~35us/step floor)
    {
      float p0 = 0.f, p1 = 0.f, p2 = 0.f, p3 = 0.f;
      #pragma unroll
      for (int j = 0; j < 16; ++j) {
        float hv = hl_lds[ub * 17 + j];
        const float4 wv = *(const float4*)(&wsm_lds[j * 128 + um * 4]);
        p0 = fmaf(hv, wv.x, p0); p1 = fmaf(hv, wv.y, p1);
        p2 = fmaf(hv, wv.z, p2); p3 = fmaf(hv, wv.w, p3);
      }
      float* dst = lpart
          + (((size_t)(t & 1) * NBLK) + (grp * 32 + jt)) * (BT * NCLS)
          + (size_t)ub * NCLS + um * 4;
      st_dev16(dst, make_float4(p0, p1, p2, p3));
    }

    // ---- group barrier: relaxed flags only — NO threadfence / acquire.
    // __syncthreads drains vmcnt per wave, so h stores / lpart stores are
    // ack'd at the coherence point before tid0's flag store.
    __syncthreads();
    if (tid == 0)
      __hip_atomic_store(myflag, (unsigned)(t + 1),
                         __ATOMIC_RELAXED, __HIP_MEMORY_SCOPE_AGENT);
    if (((t + 1) & (KCH - 1)) == 0 && t + 1 < TLEN)
      chunk_gemm(t + 1);                // heavy, recurrence-independent work
    if (tid < 64) {
      const unsigned tgt = (unsigned)(t + 1);
      for (;;) {
        unsigned v = __hip_atomic_load(pollflag, __ATOMIC_RELAXED,
                                       __HIP_MEMORY_SCOPE_AGENT);
        if (__all(v >= tgt)) break;
        __builtin_amdgcn_s_sleep(1);
      }
    }
    __syncthreads();   // also separates chunk-GEMM Wt reads from next-step LDS writes
  }

  // ---- epilogue: argmax for final step (buf (TLEN-1)&1 == 1)
  if (jt == 0) {
    const float* pb = lpart
        + (((size_t)((TLEN - 1) & 1) * NBLK) + grp * 32) * (BT * NCLS)
        + (size_t)ub * NCLS + um * 4;
    float4 s0 = make_float4(0.f, 0.f, 0.f, 0.f);
    float4 s1 = s0, s2 = s0, s3 = s0;
    #pragma unroll 1
    for (int j2 = 0; j2 < 32; j2 += 4) {
      float4 a = ld_dev16(pb + (size_t)(j2 + 0) * (BT * NCLS));
      float4 b = ld_dev16(pb + (size_t)(j2 + 1) * (BT * NCLS));
      float4 c = ld_dev16(pb + (size_t)(j2 + 2) * (BT * NCLS));
      float4 d = ld_dev16(pb + (size_t)(j2 + 3) * (BT * NCLS));
      s0.x += a.x; s0.y += a.y; s0.z += a.z; s0.w += a.w;
      s1.x += b.x; s1.y += b.y; s1.z += b.z; s1.w += b.w;
      s2.x += c.x; s2.y += c.y; s2.z += c.z; s2.w += c.w;
      s3.x += d.x; s3.y += d.y; s3.z += d.z; s3.w += d.w;
    }
    float4 lv;
    lv.x = (s0.x + s1.x) + (s2.x + s3.x);
    lv.y = (s0.y + s1.y) + (s2.y + s3.y);
    lv.z = (s0.z + s1.z) + (s2.z + s3.z);
    lv.w = (s0.w + s1.w) + (s2.w + s3.w);
    const float4 bb = *(const float4*)(bsv + um * 4);
    float bv = lv.x + bb.x; int bi = um * 4;
    if (lv.y + bb.y > bv) { bv = lv.y + bb.y; bi = um * 4 + 1; }
    if (lv.z + bb.z > bv) { bv = lv.z + bb.z; bi = um * 4 + 2; }
    if (lv.w + bb.w > bv) { bv = lv.w + bb.w; bi = um * 4 + 3; }
    __syncthreads();
    red_v[ub * 33 + um] = bv; red_i[ub * 33 + um] = bi;
    __syncthreads();
    if (um == 0) {
      float v = red_v[ub * 33]; int vi = red_i[ub * 33];
      #pragma unroll
      for (int s = 1; s < 32; ++s) {
        float v2 = red_v[ub * 33 + s];
        int   i2 = red_i[ub * 33 + s];
        if (v2 > v || (v2 == v && i2 < vi)) { v = v2; vi = i2; }
      }
      out[(b0 + ub) * TLEN + (TLEN - 1)] = vi;
    }
  }
}

extern "C" void kernel_launch(void* const* d_in, const int* in_sizes, int n_in,
                              void* d_out, int out_size, void* d_ws, size_t ws_size,
                              hipStream_t stream) {
  (void)in_sizes; (void)n_in; (void)out_size; (void)ws_size;
  const float* xc  = (const float*)d_in[0];
  const float* xw  = (const float*)d_in[1];
  const float* W   = (const float*)d_in[2];
  const float* U   = (const float*)d_in[3];
  const float* b   = (const float*)d_in[4];
  const float* Wsm = (const float*)d_in[5];
  const float* bs  = (const float*)d_in[6];
  int*   out = (int*)d_out;
  float* ws  = (float*)d_ws;

  hipLaunchKernelGGL(setup_kernel, dim3(64), dim3(256), 0, stream, W, b, ws);

  void* args[] = { (void*)&xc, (void*)&xw, (void*)&W, (void*)&U, (void*)&b,
                   (void*)&Wsm, (void*)&bs, (void*)&out, (void*)&ws };
  hipLaunchCooperativeKernel((const void*)lstm_main, dim3(NBLK), dim3(NTHR),
                             args, 0, stream);
}

// Round 7
// 7722.368 us; speedup vs baseline: 1.1818x; 1.1818x over previous
//
#include <hip/hip_runtime.h>
#include <math.h>

// Problem dims
#define BSZ   128
#define TLEN  256
#define NCLS  128
#define WDIM  512
#define XDIM  640       // NC + WD
#define G4    2048      // 4*UNITS

// Geometry: 8 batch-groups (XCD-local) x 32 j-tiles = 256 blocks, 512 threads
#define BT    16        // batch rows per group
#define JTS   16        // h columns per block
#define NBLK  256
#define NTHR  512
#define KCH   8         // chunk length (steps of x-projection kept in regs)

// ws layout (float offsets) — total ~4.7 MB (IC-resident)
#define H_OFF     0                   // 2 * 128 * 512 h double buffer
#define LPART_OFF 131072              // 2 buf * 256 blk * 16 * 128 partials
#define W0_OFF    1179648             // 2048: bias + 1e-5*colsum(W[640:768])
#define FLAG_OFF  1181696             // 256 flags, stride 16 u32 (64B lines)

typedef unsigned long long ull;

__device__ __forceinline__ float sigmoidf_(float x) {
  return 1.0f / (1.0f + expf(-x));
}

// relaxed device-scope 16B load as 2x b64 atomics (IC-coherent, NO buffer_inv)
__device__ __forceinline__ float4 ld_dev16(const float* p) {
  const ull* q = (const ull*)p;
  ull a = __hip_atomic_load(q,     __ATOMIC_RELAXED, __HIP_MEMORY_SCOPE_AGENT);
  ull b = __hip_atomic_load(q + 1, __ATOMIC_RELAXED, __HIP_MEMORY_SCOPE_AGENT);
  float4 r;
  ((ull*)&r)[0] = a;
  ((ull*)&r)[1] = b;
  return r;
}

// relaxed device-scope 16B store as 2x b64 atomics (lands at IC, no RMW)
__device__ __forceinline__ void st_dev16(float* p, float4 v) {
  ull* q = (ull*)p;
  __hip_atomic_store(q,     ((ull*)&v)[0], __ATOMIC_RELAXED, __HIP_MEMORY_SCOPE_AGENT);
  __hip_atomic_store(q + 1, ((ull*)&v)[1], __ATOMIC_RELAXED, __HIP_MEMORY_SCOPE_AGENT);
}

__global__ void setup_kernel(const float* __restrict__ W,
                             const float* __restrict__ bias,
                             float* __restrict__ ws) {
  int tid = blockIdx.x * blockDim.x + threadIdx.x;   // 64*256 = 16384 threads
  if (tid < 4096)
    ((unsigned int*)(ws + FLAG_OFF))[tid] = 0u;
  if (tid < G4) {
    float s = 0.0f;
    #pragma unroll 4
    for (int r = 0; r < NCLS; ++r)
      s += W[(size_t)(XDIM + r) * G4 + tid];
    ws[W0_OFF + tid] = bias[tid] + 1e-5f * s;
  }
}

__global__ void __launch_bounds__(NTHR, 1)
lstm_main(const float* __restrict__ xc, const float* __restrict__ xw,
          const float* __restrict__ W,  const float* __restrict__ U,
          const float* __restrict__ bias, const float* __restrict__ Wsm,
          const float* __restrict__ bsv, int* __restrict__ out,
          float* __restrict__ ws)
{
  __shared__ float U_lds[512 * 64];      // 128 KB resident U tile [k][cc]
  __shared__ float ins_lds[2][2176];     // staging/zred; chunk GEMM W-tile alias
  __shared__ float wsm_lds[16 * 128];    // resident Wsm tile [j][m]
  __shared__ float hl_lds[16 * 17];      // h_new tile [b][16], padded
  __shared__ int   idx_lds[BT];

  float* zred  = &ins_lds[0][0];         // z exchange [32][68] (2176 floats)
  float* Wt    = &ins_lds[0][0];         // chunk GEMM W-tile [64][64] (4096 fl)
  float* red_v = zred;                   // argmax scratch [16][33] (epilogue)
  int*   red_i = (int*)(zred + 528);     // [16][33]

  const int tid = threadIdx.x;
  const int blk = blockIdx.x;
  const int grp = blk & 7;               // batch group (XCD-local heuristic)
  const int jt  = blk >> 3;              // 0..31 j-tile
  const int b0  = grp * BT;
  const int j0  = jt * JTS;

  // GEMM mapping: thread = (batch row gb, gate gg, 4-col group j4, K-half kh)
  const int gb  = tid & 15;
  const int gg  = (tid >> 4) & 3;
  const int j4  = (tid >> 6) & 3;
  const int kh  = tid >> 8;                 // 0..1
  const int c0  = gg * 512 + j0 + j4 * 4;   // global column in [0,2048)
  const int cc0 = gg * 16 + j4 * 4;         // LDS column in [0,64)

  // staging mapping: thread = (row srow, 4-float seg sseg)
  const int srow = tid >> 5;                // 0..15
  const int sseg = tid & 31;                // 0..31

  // logits/argmax mapping: thread = (row ub, class-quad um)
  const int ub = tid >> 5;
  const int um = tid & 31;

  // update mapping (tid < 256): thread = (row vb, h-col vj)
  const int vb = (tid >> 4) & 15;
  const int vj = tid & 15;

  float* hbuf   = ws + H_OFF;
  float* lpart  = ws + LPART_OFF;
  unsigned int* flags = (unsigned int*)(ws + FLAG_OFF);
  unsigned int* myflag   = flags + (grp * 32 + jt) * 16;
  unsigned int* pollflag = flags + (grp * 32 + (tid & 31)) * 16;

  // Load resident U tile: U_lds[k*64 + cc] = U[k][col(cc)]
  {
    int cc  = tid & 63;
    int col = (cc >> 4) * 512 + j0 + (cc & 15);
    int k0  = tid >> 6;  // 0..7
    for (int kk = 0; kk < 64; ++kk) {
      int k = kk * 8 + k0;
      U_lds[k * 64 + cc] = U[(size_t)k * G4 + col];
    }
  }
  // Load resident Wsm tile: wsm_lds[j][m]
  {
    int row = tid >> 5, col4 = tid & 31;
    *(float4*)(&wsm_lds[row * 128 + col4 * 4]) =
        *(const float4*)(Wsm + (size_t)(j0 + row) * NCLS + col4 * 4);
  }

  // ---- chunk GEMM (R9 SB=4 s-blocked, proven clean):
  // per k-quad, 4 NAMED float4 W values read once from LDS, reused across
  // 4 steps -> 640 ds_read_b128/thread/chunk. SCRATCH DISCIPLINE (ledger):
  // compile-time local-array indices only; hot set ~80 VGPR; sched_barrier
  // caps load clustering. FMA order = R0's -> bitwise-identical.
  float4 xq[KCH];
  auto chunk_gemm = [&](int tt0) {
    #pragma unroll
    for (int s = 0; s < KCH; ++s) xq[s] = make_float4(0.f, 0.f, 0.f, 0.f);
    #pragma unroll 1
    for (int kt = 0; kt < 10; ++kt) {          // ten 64-deep k-tiles
      int id0 = tid,       k0t = id0 >> 4, cg0 = id0 & 15;
      int id1 = tid + 512, k1t = id1 >> 4, cg1 = id1 & 15;
      int col0 = (cg0 >> 2) * 512 + j0 + (cg0 & 3) * 4;
      int col1 = (cg1 >> 2) * 512 + j0 + (cg1 & 3) * 4;
      float4 wv0 = *(const float4*)(W + (size_t)(kt * 64 + k0t) * G4 + col0);
      float4 wv1 = *(const float4*)(W + (size_t)(kt * 64 + k1t) * G4 + col1);
      __syncthreads();                         // prior Wt readers done
      *(float4*)(Wt + k0t * 64 + cg0 * 4) = wv0;
      *(float4*)(Wt + k1t * 64 + cg1 * 4) = wv1;
      __syncthreads();                         // tile visible
      const float* wp = Wt + (kh * 32) * 64 + cc0;
      const float* xb0 = (kt < 2)
        ? xc + ((size_t)(b0 + gb) * TLEN + tt0) * NCLS + kt * 64 + kh * 32
        : xw + ((size_t)(b0 + gb) * TLEN + tt0) * WDIM + (kt * 64 - 128) + kh * 32;
      const size_t xstr = (kt < 2) ? (size_t)NCLS : (size_t)WDIM;
      #pragma unroll
      for (int sb = 0; sb < 2; ++sb) {         // two s-blocks of 4 steps
        #pragma unroll 1
        for (int q = 0; q < 8; ++q) {          // 8 k-quads of this K-half
          const float* wq = wp + q * 4 * 64;
          float4 w0 = *(const float4*)(wq);
          float4 w1 = *(const float4*)(wq + 64);
          float4 w2 = *(const float4*)(wq + 128);
          float4 w3 = *(const float4*)(wq + 192);
          const float* xquad = xb0 + (size_t)(sb * 4) * xstr + q * 4;
          #pragma unroll
          for (int u = 0; u < 4; ++u) {
            const int s = sb * 4 + u;          // compile-time index
            float4 xa = *(const float4*)(xquad + (size_t)u * xstr);
            xq[s].x = fmaf(xa.x, w0.x, xq[s].x);
            xq[s].y = fmaf(xa.x, w0.y, xq[s].y);
            xq[s].z = fmaf(xa.x, w0.z, xq[s].z);
            xq[s].w = fmaf(xa.x, w0.w, xq[s].w);
            xq[s].x = fmaf(xa.y, w1.x, xq[s].x);
            xq[s].y = fmaf(xa.y, w1.y, xq[s].y);
            xq[s].z = fmaf(xa.y, w1.z, xq[s].z);
            xq[s].w = fmaf(xa.y, w1.w, xq[s].w);
            xq[s].x = fmaf(xa.z, w2.x, xq[s].x);
            xq[s].y = fmaf(xa.z, w2.y, xq[s].y);
            xq[s].z = fmaf(xa.z, w2.z, xq[s].z);
            xq[s].w = fmaf(xa.z, w2.w, xq[s].w);
            xq[s].x = fmaf(xa.w, w3.x, xq[s].x);
            xq[s].y = fmaf(xa.w, w3.y, xq[s].y);
            xq[s].z = fmaf(xa.w, w3.z, xq[s].z);
            xq[s].w = fmaf(xa.w, w3.w, xq[s].w);
          }
          __builtin_amdgcn_sched_barrier(0);   // cap load clustering here
        }
      }
    }
  };

  float creg = 0.0f;      // cell state: thread(<256) owns (b0+vb, j0+vj)

  __syncthreads();        // U_lds / wsm_lds ready
  chunk_gemm(0);          // steps 0..7
  __syncthreads();        // Wt readers done before zred reuse

  for (int t = 0; t < TLEN; ++t) {
    float4 acc = xq[0];
    #pragma unroll
    for (int s = 0; s < KCH - 1; ++s) xq[s] = xq[s + 1];   // shift register

    if (t == 0) {
      if (kh == 0) {
        const float4 w0 = *(const float4*)(ws + W0_OFF + c0);
        acc.x += w0.x; acc.y += w0.y; acc.z += w0.z; acc.w += w0.w;
      }
    } else {
      // ---- R11: h@U with the lpart (argmax) reduce OVERLAPPED into it.
      // The argmax reduce is independent of h@U (feeds only the word-row
      // add at the end). R6 ran it as a serialized 8-round IC latency
      // chain BEFORE h@U (+1.3us/step measured — the kernel is serial-
      // latency-bound, not throughput-bound: LDS 4x cut and atomic
      // removal both Δ=0). Here each ch issues a 4-slot ld_dev16 batch
      // before each 32-iter FMA half-loop and consumes it after (~800cyc
      // cover). Chain order identical to R6 (batches ascending, slot c
      // -> s_c) -> bitwise-identical logits. Serial scan replaced by a
      // 5-round shfl_xor butterfly (same total-order comparator ->
      // identical argmax), removing the red_v/red_i LDS round trip and
      // one barrier. NOTE: bias+word-row now added AFTER the U FMAs
      // (idx arrives late) — rounding-level order change only.
      const float* pb = lpart
          + (((size_t)((t - 1) & 1) * NBLK) + grp * 32) * (BT * NCLS)
          + (size_t)ub * NCLS + um * 4;
      float4 s0 = make_float4(0.f, 0.f, 0.f, 0.f);
      float4 s1 = s0, s2 = s0, s3 = s0;
      const float* hprev = hbuf + ((t + 1) & 1) * (BSZ * 512);
      {
        float4 r = ld_dev16(hprev + (size_t)(b0 + srow) * 512 + sseg * 4);
        *(float4*)(&ins_lds[0][srow * 132 + sseg * 4]) = r;
        __syncthreads();
      }
      #pragma unroll 1
      for (int ch = 0; ch < 4; ++ch) {
        float4 nxt;
        if (ch + 1 < 4) {
          nxt = ld_dev16(hprev + (size_t)(b0 + srow) * 512
                         + (ch + 1) * 128 + sseg * 4);
        }
        const float* up = U_lds + (ch * 128 + kh * 64) * 64 + cc0;
        const float* ip = &ins_lds[ch & 1][gb * 132 + kh * 64];
        // batch A = slots 8ch..8ch+3 (issued before FMA half 1)
        const float* pbA = pb + (size_t)(8 * ch) * (BT * NCLS);
        float4 A0 = ld_dev16(pbA + (size_t)0 * (BT * NCLS));
        float4 A1 = ld_dev16(pbA + (size_t)1 * (BT * NCLS));
        float4 A2 = ld_dev16(pbA + (size_t)2 * (BT * NCLS));
        float4 A3 = ld_dev16(pbA + (size_t)3 * (BT * NCLS));
        #pragma unroll 8
        for (int kk = 0; kk < 32; ++kk) {
          float a = ip[kk];
          float4 u4 = *(const float4*)(up + kk * 64);
          acc.x = fmaf(a, u4.x, acc.x);
          acc.y = fmaf(a, u4.y, acc.y);
          acc.z = fmaf(a, u4.z, acc.z);
          acc.w = fmaf(a, u4.w, acc.w);
        }
        s0.x += A0.x; s0.y += A0.y; s0.z += A0.z; s0.w += A0.w;
        s1.x += A1.x; s1.y += A1.y; s1.z += A1.z; s1.w += A1.w;
        s2.x += A2.x; s2.y += A2.y; s2.z += A2.z; s2.w += A2.w;
        s3.x += A3.x; s3.y += A3.y; s3.z += A3.z; s3.w += A3.w;
        __builtin_amdgcn_sched_barrier(0);     // pin B-issue below consume-A
        // batch B = slots 8ch+4..8ch+7 (issued before FMA half 2)
        const float* pbB = pb + (size_t)(8 * ch + 4) * (BT * NCLS);
        float4 B0 = ld_dev16(pbB + (size_t)0 * (BT * NCLS));
        float4 B1 = ld_dev16(pbB + (size_t)1 * (BT * NCLS));
        float4 B2 = ld_dev16(pbB + (size_t)2 * (BT * NCLS));
        float4 B3 = ld_dev16(pbB + (size_t)3 * (BT * NCLS));
        #pragma unroll 8
        for (int kk = 32; kk < 64; ++kk) {
          float a = ip[kk];
          float4 u4 = *(const float4*)(up + kk * 64);
          acc.x = fmaf(a, u4.x, acc.x);
          acc.y = fmaf(a, u4.y, acc.y);
          acc.z = fmaf(a, u4.z, acc.z);
          acc.w = fmaf(a, u4.w, acc.w);
        }
        s0.x += B0.x; s0.y += B0.y; s0.z += B0.z; s0.w += B0.w;
        s1.x += B1.x; s1.y += B1.y; s1.z += B1.z; s1.w += B1.w;
        s2.x += B2.x; s2.y += B2.y; s2.z += B2.z; s2.w += B2.w;
        s3.x += B3.x; s3.y += B3.y; s3.z += B3.z; s3.w += B3.w;
        __builtin_amdgcn_sched_barrier(0);
        if (ch + 1 < 4) {
          *(float4*)(&ins_lds[(ch + 1) & 1][srow * 132 + sseg * 4]) = nxt;
          __syncthreads();
        }
      }
      // ---- combine + bias + per-quad argmax + shfl-scan over um (32 lanes)
      {
        float4 lv;
        lv.x = (s0.x + s1.x) + (s2.x + s3.x);
        lv.y = (s0.y + s1.y) + (s2.y + s3.y);
        lv.z = (s0.z + s1.z) + (s2.z + s3.z);
        lv.w = (s0.w + s1.w) + (s2.w + s3.w);
        const float4 bb = *(const float4*)(bsv + um * 4);
        float bv = lv.x + bb.x; int bi = um * 4;
        if (lv.y + bb.y > bv) { bv = lv.y + bb.y; bi = um * 4 + 1; }
        if (lv.z + bb.z > bv) { bv = lv.z + bb.z; bi = um * 4 + 2; }
        if (lv.w + bb.w > bv) { bv = lv.w + bb.w; bi = um * 4 + 3; }
        #pragma unroll
        for (int m = 1; m < 32; m <<= 1) {   // butterfly max, first-idx ties
          float ov = __shfl_xor(bv, m, 64);
          int   oi = __shfl_xor(bi, m, 64);
          if (ov > bv || (ov == bv && oi < bi)) { bv = ov; bi = oi; }
        }
        if (um == 0) {
          idx_lds[ub] = bi;
          if (jt == 0) out[(b0 + ub) * TLEN + (t - 1)] = bi;
        }
        __syncthreads();                     // idx_lds visible; ins_lds[0] free
      }
      // ---- bias + one-hot word row of W (K-half 0 only)
      if (kh == 0) {
        int wr = XDIM + idx_lds[gb];
        const float4 b4 = *(const float4*)(bias + c0);
        const float4 w4 = *(const float4*)(W + (size_t)wr * G4 + c0);
        acc.x += b4.x + w4.x;  acc.y += b4.y + w4.y;
        acc.z += b4.z + w4.z;  acc.w += b4.w + w4.w;
      }
    }

    // ---- z exchange into zred (= ins_lds[0]; last read at ch2, barrier since)
    *(float4*)(zred + (gb * 2 + kh) * 68 + cc0) = acc;
    __syncthreads();

    // ---- gate nonlinearities + cell/hidden update (first 256 threads)
    if (tid < 256) {
      float zi = zred[(vb * 2) * 68 +  0 + vj] + zred[(vb * 2 + 1) * 68 +  0 + vj];
      float zf = zred[(vb * 2) * 68 + 16 + vj] + zred[(vb * 2 + 1) * 68 + 16 + vj];
      float zg = zred[(vb * 2) * 68 + 32 + vj] + zred[(vb * 2 + 1) * 68 + 32 + vj];
      float zo = zred[(vb * 2) * 68 + 48 + vj] + zred[(vb * 2 + 1) * 68 + 48 + vj];
      float iv = sigmoidf_(zi);
      float fv = sigmoidf_(zf);
      float gv = tanhf(zg);
      float ov = sigmoidf_(zo);
      creg = fv * creg + iv * gv;
      float hn = ov * tanhf(creg);
      // relaxed device-scope store -> lands at IC, visible after vmcnt drain
      __hip_atomic_store(hbuf + (t & 1) * (BSZ * 512)
                         + (size_t)(b0 + vb) * 512 + j0 + vj, hn,
                         __ATOMIC_RELAXED, __HIP_MEMORY_SCOPE_AGENT);
      hl_lds[vb * 17 + vj] = hn;
    }
    __syncthreads();

    // ---- logits partial over this block's 16 j -> PRIVATE slot store
    {
      float p0 = 0.f, p1 = 0.f, p2 = 0.f, p3 = 0.f;
      #pragma unroll
      for (int j = 0; j < 16; ++j) {
        float hv = hl_lds[ub * 17 + j];
        const float4 wv = *(const float4*)(&wsm_lds[j * 128 + um * 4]);
        p0 = fmaf(hv, wv.x, p0); p1 = fmaf(hv, wv.y, p1);
        p2 = fmaf(hv, wv.z, p2); p3 = fmaf(hv, wv.w, p3);
      }
      float* dst = lpart
          + (((size_t)(t & 1) * NBLK) + (grp * 32 + jt)) * (BT * NCLS)
          + (size_t)ub * NCLS + um * 4;
      st_dev16(dst, make_float4(p0, p1, p2, p3));
    }

    // ---- group barrier: relaxed flags only. __syncthreads drains vmcnt so
    // h stores / lpart stores are IC-ack'd before tid0's flag store.
    __syncthreads();
    if (tid == 0)
      __hip_atomic_store(myflag, (unsigned)(t + 1),
                         __ATOMIC_RELAXED, __HIP_MEMORY_SCOPE_AGENT);
    if (((t + 1) & (KCH - 1)) == 0 && t + 1 < TLEN)
      chunk_gemm(t + 1);                // heavy, recurrence-independent work
    if (tid < 64) {
      const unsigned tgt = (unsigned)(t + 1);
      for (;;) {
        unsigned v = __hip_atomic_load(pollflag, __ATOMIC_RELAXED,
                                       __HIP_MEMORY_SCOPE_AGENT);
        if (__all(v >= tgt)) break;
        __builtin_amdgcn_s_sleep(1);
      }
    }
    __syncthreads();   // also separates chunk-GEMM Wt reads from next LDS writes
  }

  // ---- epilogue: argmax for final step (buf (TLEN-1)&1 == 1)
  if (jt == 0) {
    const float* pb = lpart
        + (((size_t)((TLEN - 1) & 1) * NBLK) + grp * 32) * (BT * NCLS)
        + (size_t)ub * NCLS + um * 4;
    float4 s0 = make_float4(0.f, 0.f, 0.f, 0.f);
    float4 s1 = s0, s2 = s0, s3 = s0;
    #pragma unroll 1
    for (int j2 = 0; j2 < 32; j2 += 4) {
      float4 a = ld_dev16(pb + (size_t)(j2 + 0) * (BT * NCLS));
      float4 b = ld_dev16(pb + (size_t)(j2 + 1) * (BT * NCLS));
      float4 c = ld_dev16(pb + (size_t)(j2 + 2) * (BT * NCLS));
      float4 d = ld_dev16(pb + (size_t)(j2 + 3) * (BT * NCLS));
      s0.x += a.x; s0.y += a.y; s0.z += a.z; s0.w += a.w;
      s1.x += b.x; s1.y += b.y; s1.z += b.z; s1.w += b.w;
      s2.x += c.x; s2.y += c.y; s2.z += c.z; s2.w += c.w;
      s3.x += d.x; s3.y += d.y; s3.z += d.z; s3.w += d.w;
    }
    float4 lv;
    lv.x = (s0.x + s1.x) + (s2.x + s3.x);
    lv.y = (s0.y + s1.y) + (s2.y + s3.y);
    lv.z = (s0.z + s1.z) + (s2.z + s3.z);
    lv.w = (s0.w + s1.w) + (s2.w + s3.w);
    const float4 bb = *(const float4*)(bsv + um * 4);
    float bv = lv.x + bb.x; int bi = um * 4;
    if (lv.y + bb.y > bv) { bv = lv.y + bb.y; bi = um * 4 + 1; }
    if (lv.z + bb.z > bv) { bv = lv.z + bb.z; bi = um * 4 + 2; }
    if (lv.w + bb.w > bv) { bv = lv.w + bb.w; bi = um * 4 + 3; }
    #pragma unroll
    for (int m = 1; m < 32; m <<= 1) {
      float ov = __shfl_xor(bv, m, 64);
      int   oi = __shfl_xor(bi, m, 64);
      if (ov > bv || (ov == bv && oi < bi)) { bv = ov; bi = oi; }
    }
    if (um == 0)
      out[(b0 + ub) * TLEN + (TLEN - 1)] = bi;
  }
}

extern "C" void kernel_launch(void* const* d_in, const int* in_sizes, int n_in,
                              void* d_out, int out_size, void* d_ws, size_t ws_size,
                              hipStream_t stream) {
  (void)in_sizes; (void)n_in; (void)out_size; (void)ws_size;
  const float* xc  = (const float*)d_in[0];
  const float* xw  = (const float*)d_in[1];
  const float* W   = (const float*)d_in[2];
  const float* U   = (const float*)d_in[3];
  const float* b   = (const float*)d_in[4];
  const float* Wsm = (const float*)d_in[5];
  const float* bs  = (const float*)d_in[6];
  int*   out = (int*)d_out;
  float* ws  = (float*)d_ws;

  hipLaunchKernelGGL(setup_kernel, dim3(64), dim3(256), 0, stream, W, b, ws);

  void* args[] = { (void*)&xc, (void*)&xw, (void*)&W, (void*)&U, (void*)&b,
                   (void*)&Wsm, (void*)&bs, (void*)&out, (void*)&ws };
  hipLaunchCooperativeKernel((const void*)lstm_main, dim3(NBLK), dim3(NTHR),
                             args, 0, stream);
}